// Round 9
// baseline (737.582 us; speedup 1.0000x reference)
//
#include <hip/hip_runtime.h>
#include <stdint.h>

// z: [16,1024,256] fp32 -> N=16384 rows, D=256
// embedding: [8192,256] fp32 -> K=8192 codes
// out = [ z_q (4194304 f32) | loss (1 f32) | indices (16384 as f32) ]
#define N_ROWS   16384
#define DIM      256
#define N_CODES  8192
#define ZQ_ELEMS 4194304

typedef _Float16 f16x8 __attribute__((ext_vector_type(8)));
typedef _Float16 f16x4 __attribute__((ext_vector_type(4)));
typedef float    f32x16 __attribute__((ext_vector_type(16)));
typedef unsigned long long u64;

// ---- workspace (bytes): e_tiled 66 slabs (8.65 MB) | pkeys 256 KB ----
// et 16-B units: slab*8192 + code. slabs 0..31 = e_hi octets, 32..63 = e_lo octets,
// 64 = aug {norm_hi, norm_lo, 0..}, 65 = zeros (aug for hi1=1 lanes).
#define WS_ET  0
#define WS_PK  (8650752)
// z tiled f16 planes (carrying -2z) live in the d_out z_q region (exactly
// 16 MB = 64 slabs x 16384 rows x 16 B), overwritten by vq_final (stream order).

static __device__ __forceinline__ void glds16(const void* gsrc, void* ldst) {
    __builtin_amdgcn_global_load_lds(
        (const __attribute__((address_space(1))) unsigned int*)gsrc,
        (__attribute__((address_space(3))) unsigned int*)ldst,
        16, 0, 0);
}

static __device__ __forceinline__ u64 packkey(float d, int c) {
    unsigned int u = __float_as_uint(d);
    u ^= ((unsigned int)((int)u >> 31)) | 0x80000000u;   // monotone float map
    return ((u64)u << 32) | (unsigned int)c;             // min => (dist, then idx)
}

// ---------------- fused prep: E (blocks 0..2047) + Z (blocks 2048..2303) ----------------
__global__ void vq_prep(const float* __restrict__ emb, const float* __restrict__ z,
                        _Float16* __restrict__ et, _Float16* __restrict__ zt,
                        float* __restrict__ loss_ptr) {
    __shared__ _Float16 shbuf[32768];            // 64 KB union
    const int t = threadIdx.x, w = t >> 6, l = t & 63;
    if (blockIdx.x < 2048) {
        if (blockIdx.x == 0 && t == 0) *loss_ptr = 0.0f;
        _Float16 (*lh)[256] = (_Float16(*)[256])shbuf;          // [4][256]
        _Float16 (*ll)[256] = (_Float16(*)[256])(shbuf + 1024); // [4][256]
        const int code = blockIdx.x * 4 + w;
        float4 v = *(const float4*)(emb + (size_t)code * DIM + l * 4);
        float xs[4] = {v.x, v.y, v.z, v.w};
        f16x4 hh, lo;
        float s = 0.0f;
        #pragma unroll
        for (int i = 0; i < 4; ++i) {
            _Float16 h = (_Float16)xs[i];
            hh[i] = h;
            lo[i] = (_Float16)(xs[i] - (float)h);
            s += xs[i] * xs[i];
        }
        *(f16x4*)&lh[w][l * 4] = hh;
        *(f16x4*)&ll[w][l * 4] = lo;
        #pragma unroll
        for (int off = 32; off > 0; off >>= 1) s += __shfl_down(s, off, 64);
        if (l == 0) {                            // aug slabs: ||e||^2 hi/lo + zeros
            _Float16 nh = (_Float16)s;
            _Float16 nl = (_Float16)(s - (float)nh);
            f16x8 aug, zr;
            #pragma unroll
            for (int i = 0; i < 8; ++i) { aug[i] = (_Float16)0; zr[i] = (_Float16)0; }
            aug[0] = nh; aug[1] = nl;
            *(f16x8*)(et + ((size_t)64 * N_CODES + code) * 8) = aug;
            *(f16x8*)(et + ((size_t)65 * N_CODES + code) * 8) = zr;
        }
        __syncthreads();
        const int p = t >> 7, g = t & 127;       // 2 planes x 4 codes x 32 octets
        const int cl = g & 3, fg = g >> 2;
        f16x8 frag = (p == 0) ? *(const f16x8*)&lh[cl][fg * 8]
                              : *(const f16x8*)&ll[cl][fg * 8];
        const size_t slab = (size_t)(p * 32 + fg);
        *(f16x8*)(et + (slab * N_CODES + blockIdx.x * 4 + cl) * 8) = frag;
    } else {
        _Float16 (*ls)[64][256] = (_Float16(*)[64][256])shbuf;  // [2][64][256]
        const int row0 = (blockIdx.x - 2048) * 64;
        #pragma unroll
        for (int j = 0; j < 16; ++j) {
            const int row = w * 16 + j;
            float4 v = *(const float4*)(z + (size_t)(row0 + row) * DIM + l * 4);
            float xs[4] = {v.x, v.y, v.z, v.w};
            f16x4 hh, lo;
            #pragma unroll
            for (int i = 0; i < 4; ++i) {
                const float m2 = -2.0f * xs[i];  // planes carry -2z
                _Float16 h = (_Float16)m2;
                hh[i] = h;
                lo[i] = (_Float16)(m2 - (float)h);
            }
            *(f16x4*)&ls[0][row][l * 4] = hh;
            *(f16x4*)&ls[1][row][l * 4] = lo;
        }
        __syncthreads();
        #pragma unroll
        for (int pass = 0; pass < 16; ++pass) {
            const int slab = pass * 4 + w;       // p*32 + fg
            const int p = slab >> 5, fg = slab & 31;
            f16x8 frag = *(const f16x8*)&ls[p][l][fg * 8];
            *(f16x8*)(zt + ((size_t)slab * N_ROWS + row0 + l) * 8) = frag;
        }
    }
}

// ---------------- main: role-swapped barrier-free K-loop (no ping-pong) ----------------
// grid 256 = 128 row-blocks x 2 code-splits; 512 threads (8 waves, 2/SIMD, 1 blk/CU).
// A = e (global direct, mt2 = 64 codes/wave), B = z (-2z, LDS 128 KB persistent, nt4).
// acc[m=code][n=zrow] => per-lane regs span codes -> register-domain argmin.
// Aug K-step adds ||e||^2 via constant-1 B => acc IS the distance.
// Register budget law (R4/R7/R8 spills): acc 128 AGPR + VGPRs must stay <= 256.
__global__ __launch_bounds__(512, 2)
void vq_main(const _Float16* __restrict__ zt, const _Float16* __restrict__ et,
             u64* __restrict__ pkeys) {
    extern __shared__ char smem[];
    _Float16* zs = (_Float16*)smem;              // unit: (slab*128 + row)*8 halves
    u64* run = (u64*)(smem + 131072);            // [8][128]

    const int tid = threadIdx.x;
    const int w = tid >> 6, L = tid & 63, lo5 = L & 31, hi1 = L >> 5;
    const int rb = blockIdx.x >> 1, sp = blockIdx.x & 1;
    const int row0 = rb * 128, codeS = sp * 4096;

    // ---- stage z once: 128 glds of 1 KB (16 per wave) ----
    #pragma unroll
    for (int i = 0; i < 16; ++i) {
        const int idx = w * 16 + i;              // 0..127
        const int slab = idx >> 1, half = idx & 1;
        glds16(zt + ((size_t)slab * N_ROWS + row0 + half * 64 + L) * 8,
               smem + ((slab * 128 + half * 64 + L) << 4));
    }
    run[tid] = ~0ULL;
    run[tid + 512] = ~0ULL;
    __syncthreads();

    f16x8 bz;                                    // aug B: B[k0]=B[k1]=1 (hi1=0), else 0
    #pragma unroll
    for (int i = 0; i < 8; ++i) bz[i] = (_Float16)0;
    if (hi1 == 0) { bz[0] = (_Float16)1; bz[1] = (_Float16)1; }

    for (int ci = 0; ci < 8; ++ci) {
        const int c0 = codeS + ci * 512 + w * 64;

        // early aug-A load (whole ksg loop covers its latency)
        f16x8 paug[2];
        #pragma unroll
        for (int mt = 0; mt < 2; ++mt)
            paug[mt] = *(const f16x8*)(et +
                ((size_t)(64 + hi1) * N_CODES + c0 + mt * 32 + lo5) * 8);

        f32x16 acc[2][4];
        #pragma unroll
        for (int mt = 0; mt < 2; ++mt)
            #pragma unroll
            for (int nt = 0; nt < 4; ++nt)
                #pragma unroll
                for (int e = 0; e < 16; ++e) acc[mt][nt][e] = 0.0f;

        #pragma unroll
        for (int ksg = 0; ksg < 16; ++ksg) {
            const int fg = 2 * ksg + hi1;        // k-octet 0..31
            // A frags direct from global (L1/L2-served, contiguous 512-B segs)
            f16x8 ah[2], al[2];
            #pragma unroll
            for (int mt = 0; mt < 2; ++mt) {
                const size_t ao = ((size_t)fg * N_CODES + c0 + mt * 32 + lo5) * 8;
                ah[mt] = *(const f16x8*)(et + ao);
                al[mt] = *(const f16x8*)(et + ao + (size_t)(32 * N_CODES) * 8);
            }
            // B frags from LDS
            f16x8 bh[4], bl[4];
            #pragma unroll
            for (int nt = 0; nt < 4; ++nt) {
                const int ro = nt * 32 + lo5;
                bh[nt] = *(const f16x8*)(zs + (size_t)(fg * 128 + ro) * 8);
                bl[nt] = *(const f16x8*)(zs + (size_t)((fg + 32) * 128 + ro) * 8);
            }
            #pragma unroll
            for (int mt = 0; mt < 2; ++mt)
                #pragma unroll
                for (int nt = 0; nt < 4; ++nt) {
                    acc[mt][nt] = __builtin_amdgcn_mfma_f32_32x32x16_f16(ah[mt], bh[nt], acc[mt][nt], 0, 0, 0);
                    acc[mt][nt] = __builtin_amdgcn_mfma_f32_32x32x16_f16(ah[mt], bl[nt], acc[mt][nt], 0, 0, 0);
                    acc[mt][nt] = __builtin_amdgcn_mfma_f32_32x32x16_f16(al[mt], bh[nt], acc[mt][nt], 0, 0, 0);
                }
        }
        // aug step: acc += ||e||^2 broadcast across rows
        #pragma unroll
        for (int mt = 0; mt < 2; ++mt)
            #pragma unroll
            for (int nt = 0; nt < 4; ++nt)
                acc[mt][nt] = __builtin_amdgcn_mfma_f32_32x32x16_f16(paug[mt], bz, acc[mt][nt], 0, 0, 0);

        // ---- fold: per-lane register argmin over codes, then xor32 + LDS merge ----
        #pragma unroll
        for (int nt = 0; nt < 4; ++nt) {
            float bm = 0.0f; int bc = 0;
            #pragma unroll
            for (int mt = 0; mt < 2; ++mt) {
                const f32x16 a = acc[mt][nt];
                float m = a[0];
                #pragma unroll
                for (int r = 1; r < 16; ++r) m = fminf(m, a[r]);
                int dsel = 0;
                #pragma unroll
                for (int r = 15; r >= 0; --r)            // keep lowest matching code
                    dsel = (a[r] == m) ? ((r & 3) + 8 * (r >> 2)) : dsel;
                const int c = c0 + mt * 32 + 4 * hi1 + dsel;
                if (mt == 0 || m < bm) { bm = m; bc = c; }
            }
            u64 k = packkey(bm, bc);
            const u64 o = __shfl_xor(k, 32, 64);         // merge code-halves
            if (o < k) k = o;
            if (hi1 == 0) {
                u64* p = &run[w * 128 + nt * 32 + lo5];  // sole writer per slot
                if (k < *p) *p = k;
            }
        }
    }

    __syncthreads();
    if (tid < 128) {
        u64 k = run[tid];
        #pragma unroll
        for (int w2 = 1; w2 < 8; ++w2) { u64 o = run[w2 * 128 + tid]; if (o < k) k = o; }
        pkeys[(size_t)sp * N_ROWS + row0 + tid] = k;
    }
}

// ---------------- final: merge 2 splits, idx, z_q gather, loss ----------------
__global__ __launch_bounds__(512)
void vq_final(const float* __restrict__ z, const float* __restrict__ emb,
              const u64* __restrict__ pkeys,
              float* __restrict__ zq_out, float* __restrict__ loss_out,
              float* __restrict__ idx_out) {
    __shared__ int best[64];
    const int t = threadIdx.x;
    const int row0 = blockIdx.x * 64;
    if (t < 64) {
        u64 k = pkeys[row0 + t];
        u64 o = pkeys[(size_t)N_ROWS + row0 + t];
        if (o < k) k = o;
        const int code = (int)(k & 0xFFFFFFFFu);
        best[t] = code;
        idx_out[row0 + t] = (float)code;
    }
    __syncthreads();
    const int wave = t >> 6, lane = t & 63;
    float lsum = 0.0f;
    #pragma unroll
    for (int rr = 0; rr < 8; ++rr) {
        const int rl = wave * 8 + rr;
        const int rg = row0 + rl;
        const int code = best[rl];
        float4 ev = *(const float4*)(emb + (size_t)code * DIM + lane * 4);
        float4 zv = *(const float4*)(z   + (size_t)rg   * DIM + lane * 4);
        float dx = ev.x - zv.x, dy = ev.y - zv.y;
        float dz = ev.z - zv.z, dw = ev.w - zv.w;
        lsum += dx * dx + dy * dy + dz * dz + dw * dw;
        *(float4*)(zq_out + (size_t)rg * DIM + lane * 4) = ev;
    }
    #pragma unroll
    for (int off = 32; off > 0; off >>= 1) lsum += __shfl_down(lsum, off, 64);
    if (lane == 0) atomicAdd(loss_out, lsum * (1.25f / (float)ZQ_ELEMS));
}

extern "C" void kernel_launch(void* const* d_in, const int* in_sizes, int n_in,
                              void* d_out, int out_size, void* d_ws, size_t ws_size,
                              hipStream_t stream) {
    const float* z   = (const float*)d_in[0];
    const float* emb = (const float*)d_in[1];
    float* out  = (float*)d_out;
    float* zq   = out;
    float* loss = out + ZQ_ELEMS;
    float* idx  = out + ZQ_ELEMS + 1;

    char* ws = (char*)d_ws;
    _Float16* et = (_Float16*)(ws + WS_ET);
    u64*   pk    = (u64*)(ws + WS_PK);

    // z tiled f16 planes (-2z) in the z_q output region (64 slabs * 16384 * 16 B)
    _Float16* zt = (_Float16*)zq;

    static bool attr_set = false;
    if (!attr_set) {
        hipFuncSetAttribute((const void*)vq_main,
                            hipFuncAttributeMaxDynamicSharedMemorySize, 139264);
        attr_set = true;
    }

    vq_prep<<<2304, 256, 0, stream>>>(emb, z, et, zt, loss);
    vq_main<<<256, 512, 139264, stream>>>(zt, et, pk);
    vq_final<<<N_ROWS / 64, 512, 0, stream>>>(z, emb, pk, zq, loss, idx);
}

// Round 10
// 650.242 us; speedup vs baseline: 1.1343x; 1.1343x over previous
//
#include <hip/hip_runtime.h>
#include <stdint.h>

// z: [16,1024,256] fp32 -> N=16384 rows, D=256
// embedding: [8192,256] fp32 -> K=8192 codes
// out = [ z_q (4194304 f32) | loss (1 f32) | indices (16384 as f32) ]
#define N_ROWS   16384
#define DIM      256
#define N_CODES  8192
#define ZQ_ELEMS 4194304

typedef _Float16 f16x8 __attribute__((ext_vector_type(8)));
typedef _Float16 f16x4 __attribute__((ext_vector_type(4)));
typedef float    f32x16 __attribute__((ext_vector_type(16)));
typedef unsigned long long u64;

// ---- workspace (bytes): e_tiled 66 slabs (8.65 MB) | pkeys 256 KB ----
// et 16-B units: slab*8192 + code. slabs 0..31 = e_hi octets, 32..63 = e_lo octets,
// 64 = aug {norm_hi, norm_lo, 0..}, 65 = zeros (aug for hi1=1 lanes).
#define WS_ET  0
#define WS_PK  (8650752)
// z tiled f16 planes (carrying -2z) live in the d_out z_q region (exactly
// 16 MB = 64 slabs x 16384 rows x 16 B), overwritten by vq_final (stream order).

static __device__ __forceinline__ void glds16(const void* gsrc, void* ldst) {
    __builtin_amdgcn_global_load_lds(
        (const __attribute__((address_space(1))) unsigned int*)gsrc,
        (__attribute__((address_space(3))) unsigned int*)ldst,
        16, 0, 0);
}

static __device__ __forceinline__ u64 packkey(float d, int c) {
    unsigned int u = __float_as_uint(d);
    u ^= ((unsigned int)((int)u >> 31)) | 0x80000000u;   // monotone float map
    return ((u64)u << 32) | (unsigned int)c;             // min => (dist, then idx)
}

// ---------------- fused prep: E (blocks 0..2047) + Z (blocks 2048..2303) ----------------
__global__ void vq_prep(const float* __restrict__ emb, const float* __restrict__ z,
                        _Float16* __restrict__ et, _Float16* __restrict__ zt,
                        float* __restrict__ loss_ptr) {
    __shared__ _Float16 shbuf[32768];            // 64 KB union
    const int t = threadIdx.x, w = t >> 6, l = t & 63;
    if (blockIdx.x < 2048) {
        if (blockIdx.x == 0 && t == 0) *loss_ptr = 0.0f;
        _Float16 (*lh)[256] = (_Float16(*)[256])shbuf;          // [4][256]
        _Float16 (*ll)[256] = (_Float16(*)[256])(shbuf + 1024); // [4][256]
        const int code = blockIdx.x * 4 + w;
        float4 v = *(const float4*)(emb + (size_t)code * DIM + l * 4);
        float xs[4] = {v.x, v.y, v.z, v.w};
        f16x4 hh, lo;
        float s = 0.0f;
        #pragma unroll
        for (int i = 0; i < 4; ++i) {
            _Float16 h = (_Float16)xs[i];
            hh[i] = h;
            lo[i] = (_Float16)(xs[i] - (float)h);
            s += xs[i] * xs[i];
        }
        *(f16x4*)&lh[w][l * 4] = hh;
        *(f16x4*)&ll[w][l * 4] = lo;
        #pragma unroll
        for (int off = 32; off > 0; off >>= 1) s += __shfl_down(s, off, 64);
        if (l == 0) {                            // aug slabs: ||e||^2 hi/lo + zeros
            _Float16 nh = (_Float16)s;
            _Float16 nl = (_Float16)(s - (float)nh);
            f16x8 aug, zr;
            #pragma unroll
            for (int i = 0; i < 8; ++i) { aug[i] = (_Float16)0; zr[i] = (_Float16)0; }
            aug[0] = nh; aug[1] = nl;
            *(f16x8*)(et + ((size_t)64 * N_CODES + code) * 8) = aug;
            *(f16x8*)(et + ((size_t)65 * N_CODES + code) * 8) = zr;
        }
        __syncthreads();
        const int p = t >> 7, g = t & 127;       // 2 planes x 4 codes x 32 octets
        const int cl = g & 3, fg = g >> 2;
        f16x8 frag = (p == 0) ? *(const f16x8*)&lh[cl][fg * 8]
                              : *(const f16x8*)&ll[cl][fg * 8];
        const size_t slab = (size_t)(p * 32 + fg);
        *(f16x8*)(et + (slab * N_CODES + blockIdx.x * 4 + cl) * 8) = frag;
    } else {
        _Float16 (*ls)[64][256] = (_Float16(*)[64][256])shbuf;  // [2][64][256]
        const int row0 = (blockIdx.x - 2048) * 64;
        #pragma unroll
        for (int j = 0; j < 16; ++j) {
            const int row = w * 16 + j;
            float4 v = *(const float4*)(z + (size_t)(row0 + row) * DIM + l * 4);
            float xs[4] = {v.x, v.y, v.z, v.w};
            f16x4 hh, lo;
            #pragma unroll
            for (int i = 0; i < 4; ++i) {
                const float m2 = -2.0f * xs[i];  // planes carry -2z
                _Float16 h = (_Float16)m2;
                hh[i] = h;
                lo[i] = (_Float16)(m2 - (float)h);
            }
            *(f16x4*)&ls[0][row][l * 4] = hh;
            *(f16x4*)&ls[1][row][l * 4] = lo;
        }
        __syncthreads();
        #pragma unroll
        for (int pass = 0; pass < 16; ++pass) {
            const int slab = pass * 4 + w;       // p*32 + fg
            const int p = slab >> 5, fg = slab & 31;
            f16x8 frag = *(const f16x8*)&ls[p][l][fg * 8];
            *(f16x8*)(zt + ((size_t)slab * N_ROWS + row0 + l) * 8) = frag;
        }
    }
}

// ---------------- main: role-swap + single-pass register-resident argmin ----------------
// grid 256 = 128 row-blocks x 2 code-splits; 512 threads (8 waves, 2/SIMD, 1 blk/CU).
// A = e (global direct, mt2 = 64 codes/wave), B = z (-2z, LDS 128 KB persistent, nt4).
// C[m=code][n=zrow]: a lane's row (nt*32+lo5) is FIXED across ci -> running argmin
// lives in 4 u64 registers for the whole kernel; cross-lane merge happens ONCE.
// Fold reads each acc element exactly once (R8/R9's two-pass fold forced mass
// accvgpr->vgpr copies -> spill at VGPR_Count=128; this is the fix).
__global__ __launch_bounds__(512, 2)
void vq_main(const _Float16* __restrict__ zt, const _Float16* __restrict__ et,
             u64* __restrict__ pkeys) {
    extern __shared__ char smem[];
    _Float16* zs = (_Float16*)smem;              // unit: (slab*128 + row)*8 halves
    u64* run = (u64*)(smem + 131072);            // [8][128]

    const int tid = threadIdx.x;
    const int w = tid >> 6, L = tid & 63, lo5 = L & 31, hi1 = L >> 5;
    const int rb = blockIdx.x >> 1, sp = blockIdx.x & 1;
    const int row0 = rb * 128, codeS = sp * 4096;

    // ---- stage z once: 128 glds of 1 KB (16 per wave) ----
    #pragma unroll
    for (int i = 0; i < 16; ++i) {
        const int idx = w * 16 + i;              // 0..127
        const int slab = idx >> 1, half = idx & 1;
        glds16(zt + ((size_t)slab * N_ROWS + row0 + half * 64 + L) * 8,
               smem + ((slab * 128 + half * 64 + L) << 4));
    }
    __syncthreads();

    f16x8 bz;                                    // aug B: B[k0]=B[k1]=1 (hi1=0), else 0
    #pragma unroll
    for (int i = 0; i < 8; ++i) bz[i] = (_Float16)0;
    if (hi1 == 0) { bz[0] = (_Float16)1; bz[1] = (_Float16)1; }

    u64 runk[4] = {~0ULL, ~0ULL, ~0ULL, ~0ULL};  // per-lane running (dist,code)

    for (int ci = 0; ci < 8; ++ci) {
        const int c0 = codeS + ci * 512 + w * 64;

        // early aug-A load (whole ksg loop covers its latency)
        f16x8 paug[2];
        #pragma unroll
        for (int mt = 0; mt < 2; ++mt)
            paug[mt] = *(const f16x8*)(et +
                ((size_t)(64 + hi1) * N_CODES + c0 + mt * 32 + lo5) * 8);

        f32x16 acc[2][4];
        #pragma unroll
        for (int mt = 0; mt < 2; ++mt)
            #pragma unroll
            for (int nt = 0; nt < 4; ++nt)
                #pragma unroll
                for (int e = 0; e < 16; ++e) acc[mt][nt][e] = 0.0f;

        #pragma unroll
        for (int ksg = 0; ksg < 16; ++ksg) {
            const int fg = 2 * ksg + hi1;        // k-octet 0..31
            // A frags direct from global (L1/L2-served, contiguous 512-B segs)
            f16x8 ah[2], al[2];
            #pragma unroll
            for (int mt = 0; mt < 2; ++mt) {
                const size_t ao = ((size_t)fg * N_CODES + c0 + mt * 32 + lo5) * 8;
                ah[mt] = *(const f16x8*)(et + ao);
                al[mt] = *(const f16x8*)(et + ao + (size_t)(32 * N_CODES) * 8);
            }
            // B frags from LDS
            f16x8 bh[4], bl[4];
            #pragma unroll
            for (int nt = 0; nt < 4; ++nt) {
                const int ro = nt * 32 + lo5;
                bh[nt] = *(const f16x8*)(zs + (size_t)(fg * 128 + ro) * 8);
                bl[nt] = *(const f16x8*)(zs + (size_t)((fg + 32) * 128 + ro) * 8);
            }
            #pragma unroll
            for (int mt = 0; mt < 2; ++mt)
                #pragma unroll
                for (int nt = 0; nt < 4; ++nt) {
                    acc[mt][nt] = __builtin_amdgcn_mfma_f32_32x32x16_f16(ah[mt], bh[nt], acc[mt][nt], 0, 0, 0);
                    acc[mt][nt] = __builtin_amdgcn_mfma_f32_32x32x16_f16(ah[mt], bl[nt], acc[mt][nt], 0, 0, 0);
                    acc[mt][nt] = __builtin_amdgcn_mfma_f32_32x32x16_f16(al[mt], bh[nt], acc[mt][nt], 0, 0, 0);
                }
        }
        // aug step: acc += ||e||^2 broadcast across rows => acc IS the distance
        #pragma unroll
        for (int mt = 0; mt < 2; ++mt)
            #pragma unroll
            for (int nt = 0; nt < 4; ++nt)
                acc[mt][nt] = __builtin_amdgcn_mfma_f32_32x32x16_f16(paug[mt], bz, acc[mt][nt], 0, 0, 0);

        // ---- fold: single-pass, each acc element consumed exactly once ----
        #pragma unroll
        for (int nt = 0; nt < 4; ++nt) {
            u64 best = runk[nt];
            #pragma unroll
            for (int mt = 0; mt < 2; ++mt) {
                const int cb = c0 + mt * 32 + 4 * hi1;
                #pragma unroll
                for (int r = 0; r < 16; ++r) {
                    const u64 k = packkey(acc[mt][nt][r],
                                          cb + (r & 3) + 8 * (r >> 2));
                    if (k < best) best = k;
                }
            }
            runk[nt] = best;
        }
    }

    // ---- final merge: one xor32 shuffle, one LDS write per slot, 8-way merge ----
    #pragma unroll
    for (int nt = 0; nt < 4; ++nt) {
        u64 k = runk[nt];
        const u64 o = __shfl_xor(k, 32, 64);     // merge code-halves (same row)
        if (o < k) k = o;
        if (hi1 == 0) run[w * 128 + nt * 32 + lo5] = k;   // each slot written once
    }
    __syncthreads();
    if (tid < 128) {
        u64 k = run[tid];
        #pragma unroll
        for (int w2 = 1; w2 < 8; ++w2) { u64 o = run[w2 * 128 + tid]; if (o < k) k = o; }
        pkeys[(size_t)sp * N_ROWS + row0 + tid] = k;
    }
}

// ---------------- final: merge 2 splits, idx, z_q gather, loss ----------------
__global__ __launch_bounds__(512)
void vq_final(const float* __restrict__ z, const float* __restrict__ emb,
              const u64* __restrict__ pkeys,
              float* __restrict__ zq_out, float* __restrict__ loss_out,
              float* __restrict__ idx_out) {
    __shared__ int best[64];
    const int t = threadIdx.x;
    const int row0 = blockIdx.x * 64;
    if (t < 64) {
        u64 k = pkeys[row0 + t];
        u64 o = pkeys[(size_t)N_ROWS + row0 + t];
        if (o < k) k = o;
        const int code = (int)(k & 0xFFFFFFFFu);
        best[t] = code;
        idx_out[row0 + t] = (float)code;
    }
    __syncthreads();
    const int wave = t >> 6, lane = t & 63;
    float lsum = 0.0f;
    #pragma unroll
    for (int rr = 0; rr < 8; ++rr) {
        const int rl = wave * 8 + rr;
        const int rg = row0 + rl;
        const int code = best[rl];
        float4 ev = *(const float4*)(emb + (size_t)code * DIM + lane * 4);
        float4 zv = *(const float4*)(z   + (size_t)rg   * DIM + lane * 4);
        float dx = ev.x - zv.x, dy = ev.y - zv.y;
        float dz = ev.z - zv.z, dw = ev.w - zv.w;
        lsum += dx * dx + dy * dy + dz * dz + dw * dw;
        *(float4*)(zq_out + (size_t)rg * DIM + lane * 4) = ev;
    }
    #pragma unroll
    for (int off = 32; off > 0; off >>= 1) lsum += __shfl_down(lsum, off, 64);
    if (lane == 0) atomicAdd(loss_out, lsum * (1.25f / (float)ZQ_ELEMS));
}

extern "C" void kernel_launch(void* const* d_in, const int* in_sizes, int n_in,
                              void* d_out, int out_size, void* d_ws, size_t ws_size,
                              hipStream_t stream) {
    const float* z   = (const float*)d_in[0];
    const float* emb = (const float*)d_in[1];
    float* out  = (float*)d_out;
    float* zq   = out;
    float* loss = out + ZQ_ELEMS;
    float* idx  = out + ZQ_ELEMS + 1;

    char* ws = (char*)d_ws;
    _Float16* et = (_Float16*)(ws + WS_ET);
    u64*   pk    = (u64*)(ws + WS_PK);

    // z tiled f16 planes (-2z) in the z_q output region (64 slabs * 16384 * 16 B)
    _Float16* zt = (_Float16*)zq;

    static bool attr_set = false;
    if (!attr_set) {
        hipFuncSetAttribute((const void*)vq_main,
                            hipFuncAttributeMaxDynamicSharedMemorySize, 139264);
        attr_set = true;
    }

    vq_prep<<<2304, 256, 0, stream>>>(emb, z, et, zt, loss);
    vq_main<<<256, 512, 139264, stream>>>(zt, et, pk);
    vq_final<<<N_ROWS / 64, 512, 0, stream>>>(z, emb, pk, zq, loss, idx);
}

// Round 11
// 296.382 us; speedup vs baseline: 2.4886x; 2.1939x over previous
//
#include <hip/hip_runtime.h>
#include <stdint.h>

// z: [16,1024,256] fp32 -> N=16384 rows, D=256
// embedding: [8192,256] fp32 -> K=8192 codes
// out = [ z_q (4194304 f32) | loss (1 f32) | indices (16384 as f32) ]
#define N_ROWS   16384
#define DIM      256
#define N_CODES  8192
#define ZQ_ELEMS 4194304

typedef _Float16 f16x8 __attribute__((ext_vector_type(8)));
typedef _Float16 f16x4 __attribute__((ext_vector_type(4)));
typedef float    f32x16 __attribute__((ext_vector_type(16)));
typedef unsigned long long u64;

// ---- workspace (bytes): e_tiled 66 slabs (8.65 MB) | pkeys 256 KB ----
// et 16-B units: slab*8192 + code. slabs 0..31 = e_hi octets, 32..63 = e_lo octets,
// 64 = aug {norm_hi, norm_lo, 0..}, 65 = zeros (aug for hi1=1 lanes).
#define WS_ET  0
#define WS_PK  (8650752)
// z tiled f16 planes (carrying -2z) live in the d_out z_q region (exactly
// 16 MB = 64 slabs x 16384 rows x 16 B), overwritten by vq_final (stream order).

static __device__ __forceinline__ void glds16(const void* gsrc, void* ldst) {
    __builtin_amdgcn_global_load_lds(
        (const __attribute__((address_space(1))) unsigned int*)gsrc,
        (__attribute__((address_space(3))) unsigned int*)ldst,
        16, 0, 0);
}

static __device__ __forceinline__ u64 packkey(float d, int c) {
    unsigned int u = __float_as_uint(d);
    u ^= ((unsigned int)((int)u >> 31)) | 0x80000000u;   // monotone float map
    return ((u64)u << 32) | (unsigned int)c;             // min => (dist, then idx)
}

// ---------------- fused prep: E (blocks 0..2047) + Z (blocks 2048..2303) ----------------
__global__ void vq_prep(const float* __restrict__ emb, const float* __restrict__ z,
                        _Float16* __restrict__ et, _Float16* __restrict__ zt,
                        float* __restrict__ loss_ptr) {
    __shared__ _Float16 shbuf[32768];            // 64 KB union
    const int t = threadIdx.x, w = t >> 6, l = t & 63;
    if (blockIdx.x < 2048) {
        if (blockIdx.x == 0 && t == 0) *loss_ptr = 0.0f;
        _Float16 (*lh)[256] = (_Float16(*)[256])shbuf;          // [4][256]
        _Float16 (*ll)[256] = (_Float16(*)[256])(shbuf + 1024); // [4][256]
        const int code = blockIdx.x * 4 + w;
        float4 v = *(const float4*)(emb + (size_t)code * DIM + l * 4);
        float xs[4] = {v.x, v.y, v.z, v.w};
        f16x4 hh, lo;
        float s = 0.0f;
        #pragma unroll
        for (int i = 0; i < 4; ++i) {
            _Float16 h = (_Float16)xs[i];
            hh[i] = h;
            lo[i] = (_Float16)(xs[i] - (float)h);
            s += xs[i] * xs[i];
        }
        *(f16x4*)&lh[w][l * 4] = hh;
        *(f16x4*)&ll[w][l * 4] = lo;
        #pragma unroll
        for (int off = 32; off > 0; off >>= 1) s += __shfl_down(s, off, 64);
        if (l == 0) {                            // aug slabs: ||e||^2 hi/lo + zeros
            _Float16 nh = (_Float16)s;
            _Float16 nl = (_Float16)(s - (float)nh);
            f16x8 aug, zr;
            #pragma unroll
            for (int i = 0; i < 8; ++i) { aug[i] = (_Float16)0; zr[i] = (_Float16)0; }
            aug[0] = nh; aug[1] = nl;
            *(f16x8*)(et + ((size_t)64 * N_CODES + code) * 8) = aug;
            *(f16x8*)(et + ((size_t)65 * N_CODES + code) * 8) = zr;
        }
        __syncthreads();
        const int p = t >> 7, g = t & 127;       // 2 planes x 4 codes x 32 octets
        const int cl = g & 3, fg = g >> 2;
        f16x8 frag = (p == 0) ? *(const f16x8*)&lh[cl][fg * 8]
                              : *(const f16x8*)&ll[cl][fg * 8];
        const size_t slab = (size_t)(p * 32 + fg);
        *(f16x8*)(et + (slab * N_CODES + blockIdx.x * 4 + cl) * 8) = frag;
    } else {
        _Float16 (*ls)[64][256] = (_Float16(*)[64][256])shbuf;  // [2][64][256]
        const int row0 = (blockIdx.x - 2048) * 64;
        #pragma unroll
        for (int j = 0; j < 16; ++j) {
            const int row = w * 16 + j;
            float4 v = *(const float4*)(z + (size_t)(row0 + row) * DIM + l * 4);
            float xs[4] = {v.x, v.y, v.z, v.w};
            f16x4 hh, lo;
            #pragma unroll
            for (int i = 0; i < 4; ++i) {
                const float m2 = -2.0f * xs[i];  // planes carry -2z
                _Float16 h = (_Float16)m2;
                hh[i] = h;
                lo[i] = (_Float16)(m2 - (float)h);
            }
            *(f16x4*)&ls[0][row][l * 4] = hh;
            *(f16x4*)&ls[1][row][l * 4] = lo;
        }
        __syncthreads();
        #pragma unroll
        for (int pass = 0; pass < 16; ++pass) {
            const int slab = pass * 4 + w;       // p*32 + fg
            const int p = slab >> 5, fg = slab & 31;
            f16x8 frag = *(const f16x8*)&ls[p][l][fg * 8];
            *(f16x8*)(zt + ((size_t)slab * N_ROWS + row0 + l) * 8) = frag;
        }
    }
}

// ---------------- main: role-swap, single-pass fold into LDS, capped unroll ----------------
// grid 256 = 128 row-blocks x 2 code-splits; 512 threads (8 waves, 2/SIMD, 1 blk/CU).
// A = e (global direct, mt2 = 64 codes/wave), B = z (-2z, LDS 128 KB persistent, nt4).
// Aug K-step adds ||e||^2 via constant-1 B => acc IS the distance.
// Register law (R4/R7/R8/R9/R10): acc=128 AGPR; arch VGPRs must stay <=128.
// -> no runk registers (fold RMWs LDS run[] per ci), ksg unroll capped at 4 so the
//    scheduler can't hoist 16 iterations of global A-loads into live regs.
__global__ __launch_bounds__(512, 2)
void vq_main(const _Float16* __restrict__ zt, const _Float16* __restrict__ et,
             u64* __restrict__ pkeys) {
    extern __shared__ char smem[];
    _Float16* zs = (_Float16*)smem;              // unit: (slab*128 + row)*8 halves
    u64* run = (u64*)(smem + 131072);            // [8][128]

    const int tid = threadIdx.x;
    const int w = tid >> 6, L = tid & 63, lo5 = L & 31, hi1 = L >> 5;
    const int rb = blockIdx.x >> 1, sp = blockIdx.x & 1;
    const int row0 = rb * 128, codeS = sp * 4096;

    // ---- stage z once: 128 glds of 1 KB (16 per wave) ----
    #pragma unroll
    for (int i = 0; i < 16; ++i) {
        const int idx = w * 16 + i;              // 0..127
        const int slab = idx >> 1, half = idx & 1;
        glds16(zt + ((size_t)slab * N_ROWS + row0 + half * 64 + L) * 8,
               smem + ((slab * 128 + half * 64 + L) << 4));
    }
    run[tid] = ~0ULL;
    run[tid + 512] = ~0ULL;
    __syncthreads();

    f16x8 bz;                                    // aug B: B[k0]=B[k1]=1 (hi1=0), else 0
    #pragma unroll
    for (int i = 0; i < 8; ++i) bz[i] = (_Float16)0;
    if (hi1 == 0) { bz[0] = (_Float16)1; bz[1] = (_Float16)1; }

    for (int ci = 0; ci < 8; ++ci) {
        const int c0 = codeS + ci * 512 + w * 64;

        // early aug-A load (ksg loop covers its latency)
        f16x8 paug[2];
        #pragma unroll
        for (int mt = 0; mt < 2; ++mt)
            paug[mt] = *(const f16x8*)(et +
                ((size_t)(64 + hi1) * N_CODES + c0 + mt * 32 + lo5) * 8);

        f32x16 acc[2][4];
        #pragma unroll
        for (int mt = 0; mt < 2; ++mt)
            #pragma unroll
            for (int nt = 0; nt < 4; ++nt)
                #pragma unroll
                for (int e = 0; e < 16; ++e) acc[mt][nt][e] = 0.0f;

        #pragma unroll 4
        for (int ksg = 0; ksg < 16; ++ksg) {
            const int fg = 2 * ksg + hi1;        // k-octet 0..31
            // A frags direct from global (L1/L2-served, contiguous 512-B segs)
            f16x8 ah[2], al[2];
            #pragma unroll
            for (int mt = 0; mt < 2; ++mt) {
                const size_t ao = ((size_t)fg * N_CODES + c0 + mt * 32 + lo5) * 8;
                ah[mt] = *(const f16x8*)(et + ao);
                al[mt] = *(const f16x8*)(et + ao + (size_t)(32 * N_CODES) * 8);
            }
            // B frags from LDS
            f16x8 bh[4], bl[4];
            #pragma unroll
            for (int nt = 0; nt < 4; ++nt) {
                const int ro = nt * 32 + lo5;
                bh[nt] = *(const f16x8*)(zs + (size_t)(fg * 128 + ro) * 8);
                bl[nt] = *(const f16x8*)(zs + (size_t)((fg + 32) * 128 + ro) * 8);
            }
            #pragma unroll
            for (int mt = 0; mt < 2; ++mt)
                #pragma unroll
                for (int nt = 0; nt < 4; ++nt) {
                    acc[mt][nt] = __builtin_amdgcn_mfma_f32_32x32x16_f16(ah[mt], bh[nt], acc[mt][nt], 0, 0, 0);
                    acc[mt][nt] = __builtin_amdgcn_mfma_f32_32x32x16_f16(ah[mt], bl[nt], acc[mt][nt], 0, 0, 0);
                    acc[mt][nt] = __builtin_amdgcn_mfma_f32_32x32x16_f16(al[mt], bh[nt], acc[mt][nt], 0, 0, 0);
                }
        }
        // aug step: acc += ||e||^2 broadcast across rows => acc IS the distance
        #pragma unroll
        for (int mt = 0; mt < 2; ++mt)
            #pragma unroll
            for (int nt = 0; nt < 4; ++nt)
                acc[mt][nt] = __builtin_amdgcn_mfma_f32_32x32x16_f16(paug[mt], bz, acc[mt][nt], 0, 0, 0);

        // ---- fold: single-pass (each acc element consumed once) -> LDS run RMW ----
        #pragma unroll
        for (int nt = 0; nt < 4; ++nt) {
            u64 best = ~0ULL;
            #pragma unroll
            for (int mt = 0; mt < 2; ++mt) {
                const int cb = c0 + mt * 32 + 4 * hi1;
                #pragma unroll
                for (int r = 0; r < 16; ++r) {
                    const u64 k = packkey(acc[mt][nt][r],
                                          cb + (r & 3) + 8 * (r >> 2));
                    if (k < best) best = k;
                }
            }
            const u64 o = __shfl_xor(best, 32, 64);      // merge code-halves (same row)
            if (o < best) best = o;
            if (hi1 == 0) {
                u64* p = &run[w * 128 + nt * 32 + lo5];  // sole writer per slot
                if (best < *p) *p = best;
            }
        }
    }

    __syncthreads();
    if (tid < 128) {
        u64 k = run[tid];
        #pragma unroll
        for (int w2 = 1; w2 < 8; ++w2) { u64 o = run[w2 * 128 + tid]; if (o < k) k = o; }
        pkeys[(size_t)sp * N_ROWS + row0 + tid] = k;
    }
}

// ---------------- final: merge 2 splits, idx, z_q gather, loss ----------------
__global__ __launch_bounds__(512)
void vq_final(const float* __restrict__ z, const float* __restrict__ emb,
              const u64* __restrict__ pkeys,
              float* __restrict__ zq_out, float* __restrict__ loss_out,
              float* __restrict__ idx_out) {
    __shared__ int best[64];
    const int t = threadIdx.x;
    const int row0 = blockIdx.x * 64;
    if (t < 64) {
        u64 k = pkeys[row0 + t];
        u64 o = pkeys[(size_t)N_ROWS + row0 + t];
        if (o < k) k = o;
        const int code = (int)(k & 0xFFFFFFFFu);
        best[t] = code;
        idx_out[row0 + t] = (float)code;
    }
    __syncthreads();
    const int wave = t >> 6, lane = t & 63;
    float lsum = 0.0f;
    #pragma unroll
    for (int rr = 0; rr < 8; ++rr) {
        const int rl = wave * 8 + rr;
        const int rg = row0 + rl;
        const int code = best[rl];
        float4 ev = *(const float4*)(emb + (size_t)code * DIM + lane * 4);
        float4 zv = *(const float4*)(z   + (size_t)rg   * DIM + lane * 4);
        float dx = ev.x - zv.x, dy = ev.y - zv.y;
        float dz = ev.z - zv.z, dw = ev.w - zv.w;
        lsum += dx * dx + dy * dy + dz * dz + dw * dw;
        *(float4*)(zq_out + (size_t)rg * DIM + lane * 4) = ev;
    }
    #pragma unroll
    for (int off = 32; off > 0; off >>= 1) lsum += __shfl_down(lsum, off, 64);
    if (lane == 0) atomicAdd(loss_out, lsum * (1.25f / (float)ZQ_ELEMS));
}

extern "C" void kernel_launch(void* const* d_in, const int* in_sizes, int n_in,
                              void* d_out, int out_size, void* d_ws, size_t ws_size,
                              hipStream_t stream) {
    const float* z   = (const float*)d_in[0];
    const float* emb = (const float*)d_in[1];
    float* out  = (float*)d_out;
    float* zq   = out;
    float* loss = out + ZQ_ELEMS;
    float* idx  = out + ZQ_ELEMS + 1;

    char* ws = (char*)d_ws;
    _Float16* et = (_Float16*)(ws + WS_ET);
    u64*   pk    = (u64*)(ws + WS_PK);

    // z tiled f16 planes (-2z) in the z_q output region (64 slabs * 16384 * 16 B)
    _Float16* zt = (_Float16*)zq;

    static bool attr_set = false;
    if (!attr_set) {
        hipFuncSetAttribute((const void*)vq_main,
                            hipFuncAttributeMaxDynamicSharedMemorySize, 139264);
        attr_set = true;
    }

    vq_prep<<<2304, 256, 0, stream>>>(emb, z, et, zt, loss);
    vq_main<<<256, 512, 139264, stream>>>(zt, et, pk);
    vq_final<<<N_ROWS / 64, 512, 0, stream>>>(z, emb, pk, zq, loss, idx);
}